// Round 1
// 473.168 us; speedup vs baseline: 1.1564x; 1.1564x over previous
//
#include <hip/hip_runtime.h>
#include <cstdint>
#include <cstddef>

// ScaledDotProduct: qp=q@Wq^T+bq; kp=k@Wk^T+bk; vp=v@Wv^T+bv;
// z=sigmoid(qp@kp^T/16); out=z@vp.  All GEMMs bf16 MFMA (fp32 accum).
// R5: port the three big GEMMs (vp / z / out) to the 256x256 8-phase
//     counted-vmcnt schedule (guide §5 template, T2+T3+T4+T5):
//     BK=64, 8 waves (2Mx4N), 128 KiB LDS dbuf, per-phase
//     {ds_read subtile || 1 half-tile global_load_lds -> barrier ->
//      lgkmcnt(0) -> setprio(1) 16x mfma_16x16x32 -> setprio(0) -> barrier},
//     vmcnt(6) only at K-tile boundaries (3 half-tiles in flight; never
//     drain 0 in main loop).  R4's 128^2 2-barrier loop drains vmcnt(0)
//     per 32-K step = structural ~900 TF ceiling (measured 776 TF,
//     MfmaUtil 34.5%); the 8-phase template measures 1563-1728 TF.
//     MODE0 (qp/kp, N=256) keeps the old 128^2 kernel.
//     LDS swizzle: chunk c^=(row&7) applied to BOTH global source of
//     global_load_lds (linear LDS dest) and ds_read addr -> conflict-free.

typedef __bf16 bf16;
typedef __bf16 v8bf __attribute__((ext_vector_type(8)));
typedef __bf16 v4bf __attribute__((ext_vector_type(4)));
typedef float  v16f __attribute__((ext_vector_type(16)));
typedef float  v4f  __attribute__((ext_vector_type(4)));

#define DIMV  1024
#define QKD   256
#define BATCH 4
#define SEQ   4096

#define TM 128
#define TN 128
#define BK 32

// ---------------- fp32 -> bf16 cast, 4 elems/thread ----------------
__global__ __launch_bounds__(256) void cast_f32_bf16(const float* __restrict__ in,
                                                     bf16* __restrict__ out, int n4) {
  int i = blockIdx.x * 256 + threadIdx.x;
  if (i >= n4) return;
  const float4 v = reinterpret_cast<const float4*>(in)[i];
  v4bf o;
  o[0] = (bf16)v.x; o[1] = (bf16)v.y; o[2] = (bf16)v.z; o[3] = (bf16)v.w;
  reinterpret_cast<v4bf*>(out)[i] = o;
}

__device__ __forceinline__ void gload_lds16(const void* g, void* l) {
  __builtin_amdgcn_global_load_lds((const __attribute__((address_space(1))) void*)g,
                                   (__attribute__((address_space(3))) void*)l,
                                   16, 0, 0);
}

// ---------------- old 128x128 kernel (kept for MODE 0: qp/kp) -------------
template <int MODE>
__global__ __launch_bounds__(256) void gemm_nt(
    const bf16* __restrict__ A, long As_z,
    const bf16* __restrict__ B, long Bs_z,
    const float* __restrict__ bias0, const float* __restrict__ bias1,
    void* __restrict__ Cv, long Cs_z,
    int K, int lda, int ldb, int ldc) {
  __shared__ __align__(16) bf16 As[TM * BK];  // 8 KB
  __shared__ __align__(16) bf16 Bs[TN * BK];  // 8 KB
  const int tid  = threadIdx.x;
  const int wave = tid >> 6;
  const int lane = tid & 63;
  const int zb   = blockIdx.z;
  A = A + (size_t)zb * As_z;
  B = B + (size_t)zb * Bs_z;
  const float* bias = (MODE == 0 && zb) ? bias1 : bias0;

  const int row0 = blockIdx.x * TM;
  const int col0 = blockIdx.y * TN;
  const int wm = (wave & 1) * 64;
  const int wn = (wave >> 1) * 64;
  const int l31  = lane & 31;
  const int half = lane >> 5;

  v16f acc[2][2] = {};

  const char* gA = (const char*)A;
  const char* gB = (const char*)B;
  const size_t sA = (size_t)lda * 2;
  const size_t sB = (size_t)ldb * 2;

  const int row_s = tid >> 2;
  const int qg    = (tid & 3) ^ ((row_s >> 1) & 3);
  const int kb    = qg * 16;
  char* ldsA = (char*)As + wave * 1024;
  char* ldsB = (char*)Bs + wave * 1024;

  const char* pa0 = gA + (size_t)(row0 + row_s) * sA + kb;
  const char* pa1 = gA + (size_t)(row0 + row_s + 64) * sA + kb;
  const char* pb0 = gB + (size_t)(col0 + row_s) * sB + kb;
  const char* pb1 = gB + (size_t)(col0 + row_s + 64) * sB + kb;

  const int swz  = (lane >> 1) & 3;
  const int off0 = (half ^ swz) * 8;
  const int off1 = off0 ^ 16;
  const int raA0 = (wm + l31) * BK,      raA1 = (wm + 32 + l31) * BK;
  const int raB0 = (wn + l31) * BK,      raB1 = (wn + 32 + l31) * BK;

  const int kIters = K / BK;
  for (int kt = 0; kt < kIters; ++kt) {
    gload_lds16(pa0, ldsA);
    gload_lds16(pa1, ldsA + 4096);
    gload_lds16(pb0, ldsB);
    gload_lds16(pb1, ldsB + 4096);
    pa0 += BK * 2; pa1 += BK * 2; pb0 += BK * 2; pb1 += BK * 2;
    __syncthreads();

    v8bf a[2][2], b[2][2];
    a[0][0] = *(const v8bf*)&As[raA0 + off0];
    a[0][1] = *(const v8bf*)&As[raA0 + off1];
    a[1][0] = *(const v8bf*)&As[raA1 + off0];
    a[1][1] = *(const v8bf*)&As[raA1 + off1];
    b[0][0] = *(const v8bf*)&Bs[raB0 + off0];
    b[0][1] = *(const v8bf*)&Bs[raB0 + off1];
    b[1][0] = *(const v8bf*)&Bs[raB1 + off0];
    b[1][1] = *(const v8bf*)&Bs[raB1 + off1];
#pragma unroll
    for (int kk = 0; kk < 2; ++kk)
#pragma unroll
      for (int i = 0; i < 2; ++i)
#pragma unroll
        for (int j = 0; j < 2; ++j)
          acc[i][j] = __builtin_amdgcn_mfma_f32_32x32x16_bf16(a[i][kk], b[j][kk], acc[i][j], 0, 0, 0);
    __syncthreads();
  }

#pragma unroll
  for (int i = 0; i < 2; ++i) {
    const int rb = row0 + wm + i * 32 + 4 * half;
#pragma unroll
    for (int j = 0; j < 2; ++j) {
      const int gcol = col0 + wn + j * 32 + l31;
      float badd = 0.f;
      if (MODE == 0 || MODE == 1) badd = bias[gcol];
      if (MODE == 1) {
        const int b = rb >> 12;
        bf16* cb = &((bf16*)Cv)[((size_t)(b * DIMV + gcol)) * SEQ];
        const int s0 = rb & 4095;
#pragma unroll
        for (int blk = 0; blk < 4; ++blk) {
          v4bf o;
#pragma unroll
          for (int rr = 0; rr < 4; ++rr) o[rr] = (bf16)(acc[i][j][4 * blk + rr] + badd);
          *(v4bf*)&cb[s0 + 8 * blk] = o;
        }
      } else {
#pragma unroll
        for (int blk = 0; blk < 4; ++blk)
#pragma unroll
          for (int rr = 0; rr < 4; ++rr) {
            const int grow = rb + 8 * blk + rr;
            float v = acc[i][j][4 * blk + rr];
            if (MODE == 0) {
              ((bf16*)Cv)[(size_t)zb * Cs_z + (size_t)grow * ldc + gcol] = (bf16)(v + badd);
            } else if (MODE == 2) {
              v = 1.f / (1.f + __expf(v * -0.0625f));
              ((bf16*)Cv)[(size_t)zb * Cs_z + (size_t)grow * ldc + gcol] = (bf16)v;
            } else {
              ((float*)Cv)[(size_t)zb * Cs_z + (size_t)grow * ldc + gcol] = v;
            }
          }
      }
    }
  }
}

// ---------------- 256x256 8-phase kernel (MODE 1/2/3) ---------------------
#define FENCE() asm volatile("" ::: "memory")
#define BAR8()  do { FENCE(); __builtin_amdgcn_s_barrier(); FENCE(); } while (0)
#define WAIT_LGKM0() asm volatile("s_waitcnt lgkmcnt(0)" ::: "memory")
#define WAIT_VM6()   asm volatile("s_waitcnt vmcnt(6)" ::: "memory")
#define WAIT_VM0()   asm volatile("s_waitcnt vmcnt(0)" ::: "memory")

// LDS sections (16 KiB each, per dbuf): 0=A rows0-127, 1=A rows128-255,
// 2=B rows0-127, 3=B rows128-255.  Half-tile stage order per K-tile:
// [B0,B1,A0,A1] so each region's overwrite is issued >=1 barrier after its
// last read completes (B fully read in phase0; A fully read by phase2).
template <int MODE>
__global__ __launch_bounds__(512, 2) void gemm_nt8(
    const bf16* __restrict__ A, long As_z,
    const bf16* __restrict__ B, long Bs_z,
    const float* __restrict__ bias0,
    void* __restrict__ Cv, long Cs_z,
    int K, int lda, int ldb, int ldc) {
  __shared__ __align__(16) bf16 lds[2][4][8192];  // 128 KiB
  char* ldsBase = (char*)&lds[0][0][0];
  const int tid = threadIdx.x;
  const int w   = tid >> 6;   // 0..7
  const int l   = tid & 63;
  const int zb  = blockIdx.z;
  A += (size_t)zb * As_z;
  B += (size_t)zb * Bs_z;

  const int row0 = blockIdx.x * 256;
  const int col0 = blockIdx.y * 256;
  const int wmi  = w >> 2;    // M half (0..1): wave owns 128 rows
  const int wni  = w & 3;     // N quarter (0..3): wave owns 64 cols
  const int l4 = l & 15, lh = l >> 4;

  // staging: per half-tile (128 rows x 64 cols), wave-issue wi=i*8+w covers
  // rows wi*8+(l>>3); global 16B chunk pre-swizzled cg=(l&7)^(l>>3) so the
  // linear global_load_lds dest realizes LDS slot(r,c) = chunk c^(r&7).
  const int rsub = l >> 3;
  const int cg   = (l & 7) ^ rsub;
  const size_t sA = (size_t)lda * 2, sB = (size_t)ldb * 2;
  const size_t sA64 = sA * 64, sB64 = sB * 64;
  const char* pA0 = (const char*)A + (size_t)(row0 +       w * 8 + rsub) * sA + cg * 16;
  const char* pA1 = (const char*)A + (size_t)(row0 + 128 + w * 8 + rsub) * sA + cg * 16;
  const char* pB0 = (const char*)B + (size_t)(col0 +       w * 8 + rsub) * sB + cg * 16;
  const char* pB1 = (const char*)B + (size_t)(col0 + 128 + w * 8 + rsub) * sB + cg * 16;
  const int wq = w * 1024;

  // ds_read offsets: logical (r = frag*16 + l4, chunk = kk*4 + lh) at slot
  // (chunk ^ (r&7)); r&7 == l&7.  off1 = off0 ^ 64 (chunk bit2 <-> byte 64).
  const int off0 = l4 * 128 + ((lh ^ (l & 7)) << 4);
  const int off1 = off0 ^ 64;

  v4f acc[8][4] = {};  // 8 M-frags x 4 N-frags x f32x4 (128 VGPR)

#define STAGE_K(ptr, sec, d, s64)                                   \
  do {                                                              \
    char* _lb = ldsBase + (d) * 65536 + (sec) * 16384 + wq;         \
    gload_lds16(ptr, _lb);                                          \
    gload_lds16((ptr) + (s64), _lb + 8192);                         \
    (ptr) += 128;                                                   \
  } while (0)

#define READ_A(MOFF)                                                         \
  _Pragma("unroll") for (int mm = 0; mm < 4; ++mm) {                         \
    a_[mm][0] = *(const v8bf*)(aB + ((MOFF) + mm) * 2048 + off0);            \
    a_[mm][1] = *(const v8bf*)(aB + ((MOFF) + mm) * 2048 + off1);            \
  }
#define READ_B()                                                             \
  _Pragma("unroll") for (int nn = 0; nn < 4; ++nn) {                         \
    b_[nn][0] = *(const v8bf*)(bB + nn * 2048 + off0);                       \
    b_[nn][1] = *(const v8bf*)(bB + nn * 2048 + off1);                       \
  }
#define MFMA_Q(M0, N0)                                                       \
  _Pragma("unroll") for (int mm = 0; mm < 4; ++mm)                           \
  _Pragma("unroll") for (int nn = 0; nn < 2; ++nn)                           \
  _Pragma("unroll") for (int kk = 0; kk < 2; ++kk)                           \
    acc[(M0) + mm][(N0) + nn] = __builtin_amdgcn_mfma_f32_16x16x32_bf16(     \
        a_[mm][kk], b_[(N0) + nn][kk], acc[(M0) + mm][(N0) + nn], 0, 0, 0);

  const int nt = K >> 6;  // K-tiles of 64 (callers guarantee nt >= 2)

  // prologue: tile0 fully + tile1 {B0,B1,A0} = 7 half-tiles (14 loads);
  // vmcnt(6) -> tile0's 8 loads retired.
  STAGE_K(pB0, 2, 0, sB64);
  STAGE_K(pB1, 3, 0, sB64);
  STAGE_K(pA0, 0, 0, sA64);
  STAGE_K(pA1, 1, 0, sA64);
  STAGE_K(pB0, 2, 1, sB64);
  STAGE_K(pB1, 3, 1, sB64);
  STAGE_K(pA0, 0, 1, sA64);
  WAIT_VM6();
  BAR8();

  v8bf a_[4][2], b_[4][2];

  for (int t = 0; t < nt - 1; ++t) {
    const int d  = t & 1;
    const int dn = d ^ 1;
    const char* aB = ldsBase + d * 65536 + wmi * 16384;
    const char* bB = ldsBase + d * 65536 + 32768 + (wni >> 1) * 16384 + (wni & 1) * 8192;
    const bool pf = (t < nt - 2);
    // -- phase 0: read all B + A(m0-3); stage (t+1).A1 -> buf dn
    READ_A(0);
    READ_B();
    STAGE_K(pA1, 1, dn, sA64);
    BAR8();
    WAIT_LGKM0();
    __builtin_amdgcn_s_setprio(1);
    MFMA_Q(0, 0);
    __builtin_amdgcn_s_setprio(0);
    BAR8();
    // -- phase 1: stage (t+2).B0 -> buf d
    if (pf) STAGE_K(pB0, 2, d, sB64);
    BAR8();
    WAIT_LGKM0();
    __builtin_amdgcn_s_setprio(1);
    MFMA_Q(0, 2);
    __builtin_amdgcn_s_setprio(0);
    BAR8();
    // -- phase 2: read A(m4-7); stage (t+2).B1 -> buf d
    READ_A(4);
    if (pf) STAGE_K(pB1, 3, d, sB64);
    BAR8();
    WAIT_LGKM0();
    __builtin_amdgcn_s_setprio(1);
    MFMA_Q(4, 0);
    __builtin_amdgcn_s_setprio(0);
    BAR8();
    // -- phase 3: stage (t+2).A0 -> buf d; tile-boundary counted wait
    if (pf) STAGE_K(pA0, 0, d, sA64);
    BAR8();
    WAIT_LGKM0();
    __builtin_amdgcn_s_setprio(1);
    MFMA_Q(4, 2);
    __builtin_amdgcn_s_setprio(0);
    if (pf) WAIT_VM6(); else WAIT_VM0();
    BAR8();
  }
  // tail tile (no prefetch, no barriers needed)
  {
    const int d = (nt - 1) & 1;
    const char* aB = ldsBase + d * 65536 + wmi * 16384;
    const char* bB = ldsBase + d * 65536 + 32768 + (wni >> 1) * 16384 + (wni & 1) * 8192;
    READ_A(0);
    READ_B();
    MFMA_Q(0, 0);
    MFMA_Q(0, 2);
    READ_A(4);
    MFMA_Q(4, 0);
    MFMA_Q(4, 2);
  }

  // epilogue: 16x16 C/D layout col=lane&15, row=(lane>>4)*4+reg [m89/m91]
  const int rbase = row0 + wmi * 128 + 4 * lh;
#pragma unroll
  for (int mm = 0; mm < 8; ++mm) {
    const int rb = rbase + mm * 16;
#pragma unroll
    for (int nn = 0; nn < 4; ++nn) {
      const int gcol = col0 + wni * 64 + nn * 16 + l4;
      if (MODE == 1) {
        // batch-transposed vpT store; 4 consecutive s -> one 8B store
        const int b = rb >> 12;
        bf16* cb = &((bf16*)Cv)[((size_t)(b * DIMV + gcol)) * SEQ];
        const int s0 = rb & 4095;
        const float badd = bias0[gcol];
        v4bf o;
#pragma unroll
        for (int rr = 0; rr < 4; ++rr) o[rr] = (bf16)(acc[mm][nn][rr] + badd);
        *(v4bf*)&cb[s0] = o;
      } else if (MODE == 2) {
#pragma unroll
        for (int rr = 0; rr < 4; ++rr) {
          float v = acc[mm][nn][rr];
          v = 1.f / (1.f + __expf(v * -0.0625f));  // sigmoid(v/16)
          ((bf16*)Cv)[(size_t)zb * Cs_z + (size_t)(rb + rr) * ldc + gcol] = (bf16)v;
        }
      } else {  // MODE 3: f32 out
#pragma unroll
        for (int rr = 0; rr < 4; ++rr)
          ((float*)Cv)[(size_t)zb * Cs_z + (size_t)(rb + rr) * ldc + gcol] = acc[mm][nn][rr];
      }
    }
  }
#undef STAGE_K
#undef READ_A
#undef READ_B
#undef MFMA_Q
}

extern "C" void kernel_launch(void* const* d_in, const int* in_sizes, int n_in,
                              void* d_out, int out_size, void* d_ws, size_t ws_size,
                              hipStream_t stream) {
  const float* q  = (const float*)d_in[0];
  const float* k  = (const float*)d_in[1];
  const float* v  = (const float*)d_in[2];
  const float* Wq = (const float*)d_in[3];
  const float* bq = (const float*)d_in[4];
  const float* Wk = (const float*)d_in[5];
  const float* bk = (const float*)d_in[6];
  const float* Wv = (const float*)d_in[7];
  const float* bv = (const float*)d_in[8];
  float* out = (float*)d_out;

  const size_t MB = 1024 * 1024;
  char* ws = (char*)d_ws;

  int g;
  size_t zcap;
  if (ws_size >= 188 * MB)      { g = 4; zcap = 128 * MB; }
  else if (ws_size >= 121 * MB) { g = 2; zcap = 64 * MB; }
  else                          { g = 1; zcap = 64 * MB; }

  bf16 *castA, *castB, *zbuf, *Wq16, *Wk16, *Wv16, *qp16, *kp16, *vpT;
  if (g >= 2) {
    castA = (bf16*)ws;               // 32 MB
    castB = (bf16*)(ws + 32 * MB);   // 32 MB
    zbuf  = (bf16*)ws;               // g*32 MB (casts dead by then)
    char* p = ws + zcap;
    Wq16 = (bf16*)p;             p += 524288;
    Wk16 = (bf16*)p;             p += 524288;
    Wv16 = (bf16*)p;             p += 2097152;
    qp16 = (bf16*)p;             p += 8388608;
    kp16 = (bf16*)p;             p += 8388608;
    vpT  = (bf16*)p;
  } else {
    castA = (bf16*)ws;
    zbuf  = castA;
    char* p = ws + 32 * MB;
    Wq16 = (bf16*)p;             p += 524288;
    Wk16 = (bf16*)p;             p += 524288;
    Wv16 = (bf16*)p;             p += 2097152;
    qp16 = (bf16*)p;             p += 8388608;
    kp16 = (bf16*)p;             p += 8388608;
    vpT  = (bf16*)p;
    castB = vpT;
  }

  const int NQKV = BATCH * SEQ * DIMV;  // 16777216

  auto cast = [&](const float* src, bf16* dst, int n) {
    int n4 = n / 4;
    cast_f32_bf16<<<dim3((n4 + 255) / 256), dim3(256), 0, stream>>>(src, dst, n4);
  };

  cast(Wq, Wq16, QKD * DIMV);
  cast(Wk, Wk16, QKD * DIMV);
  cast(Wv, Wv16, DIMV * DIMV);
  cast(q, castA, NQKV);  // q16
  cast(k, castB, NQKV);  // k16

  // qp/kp dual launch (old 128^2 kernel; N=256 too narrow for 256^2 tile)
  gemm_nt<0><<<dim3(BATCH * SEQ / TM, QKD / TN, 2), dim3(256), 0, stream>>>(
      castA, (long)(castB - castA), Wq16, (long)(QKD * DIMV), bq, bk,
      qp16, (long)(kp16 - qp16), DIMV, DIMV, DIMV, QKD);

  // vpT: 8-phase 256^2, flat M=16384, batch-decomposed transposed store
  cast(v, castA, NQKV);  // v16 (q16 dead)
  gemm_nt8<1><<<dim3(BATCH * SEQ / 256, DIMV / 256, 1), dim3(512), 0, stream>>>(
      castA, 0L, Wv16, 0L, bv,
      vpT, 0L, DIMV, DIMV, DIMV, 0);   // overwrites k16 if g==1 (kp done)

  // per group: z = sigmoid(qp@kp^T/16); out = z @ vp  (both 8-phase 256^2)
  const long zstride = (long)SEQ * SEQ;
  for (int ig = 0; ig < BATCH / g; ++ig) {
    const size_t b0 = (size_t)ig * g;
    gemm_nt8<2><<<dim3(SEQ / 256, SEQ / 256, g), dim3(512), 0, stream>>>(
        qp16 + b0 * SEQ * QKD, (long)(SEQ * QKD),
        kp16 + b0 * SEQ * QKD, (long)(SEQ * QKD),
        nullptr, zbuf, zstride, QKD, QKD, QKD, SEQ);
    gemm_nt8<3><<<dim3(SEQ / 256, DIMV / 256, g), dim3(512), 0, stream>>>(
        zbuf, zstride, vpT + b0 * DIMV * SEQ, (long)(DIMV * SEQ),
        nullptr, out + b0 * SEQ * DIMV, (long)(SEQ * DIMV),
        SEQ, SEQ, SEQ, DIMV);
  }
}

// Round 2
// 471.234 us; speedup vs baseline: 1.1612x; 1.0041x over previous
//
#include <hip/hip_runtime.h>
#include <cstdint>
#include <cstddef>

// ScaledDotProduct: qp=q@Wq^T+bq; kp=k@Wk^T+bk; vp=v@Wv^T+bv;
// z=sigmoid(qp@kp^T/16); out=z@vp.  All GEMMs bf16 MFMA (fp32 accum).
// R6: (1) qp/kp projection GEMM reads q/k fp32 directly (reg-staged cast ->
//     ds_write, B via global_load_lds) -- removes the q16/k16 cast passes.
//     (2) gemm_nt8: (t+2).B1 stage moved ph2->ph1 (deeper in-flight; all
//     B-reads drain in ph0 so overwrite-at-ph1 is race-free; boundary stays
//     vmcnt(6) -- t+1.A1 remains the oldest outstanding pair).
//     (3) bijective XCD-chunked swizzle (m204) + y-fastest logical order on
//     gemm_nt8 grids: co-locates cold-A-panel sharers on one XCD's L2.
// R5: 256x256 8-phase counted-vmcnt schedule (T2+T3+T4+T5) for vp/z/out.

typedef __bf16 bf16;
typedef __bf16 v8bf __attribute__((ext_vector_type(8)));
typedef __bf16 v4bf __attribute__((ext_vector_type(4)));
typedef float  v16f __attribute__((ext_vector_type(16)));
typedef float  v4f  __attribute__((ext_vector_type(4)));

#define DIMV  1024
#define QKD   256
#define BATCH 4
#define SEQ   4096

#define TM 128
#define TN 128
#define BK 32

// ---------------- fp32 -> bf16 cast, 4 elems/thread ----------------
__global__ __launch_bounds__(256) void cast_f32_bf16(const float* __restrict__ in,
                                                     bf16* __restrict__ out, int n4) {
  int i = blockIdx.x * 256 + threadIdx.x;
  if (i >= n4) return;
  const float4 v = reinterpret_cast<const float4*>(in)[i];
  v4bf o;
  o[0] = (bf16)v.x; o[1] = (bf16)v.y; o[2] = (bf16)v.z; o[3] = (bf16)v.w;
  reinterpret_cast<v4bf*>(out)[i] = o;
}

__device__ __forceinline__ void gload_lds16(const void* g, void* l) {
  __builtin_amdgcn_global_load_lds((const __attribute__((address_space(1))) void*)g,
                                   (__attribute__((address_space(3))) void*)l,
                                   16, 0, 0);
}

// ---------------- 128x128 projection GEMM with fused fp32->bf16 cast ------
// C[m,n] = sum_k Af[m,k]*B[n,k] + bias[n]  (Af fp32, B bf16; out bf16)
// zb=0 -> Af=A0f, bias=bias0; zb=1 -> Af=A1f, bias=bias1.  B offset Bs_z*zb.
// A staged via reg (float4 x2 -> cvt -> ds_write_b128, same XOR slot layout
// the gload path used); B staged via global_load_lds (already bf16).
__global__ __launch_bounds__(256) void gemm_proj(
    const float* __restrict__ A0f, const float* __restrict__ A1f,
    const bf16* __restrict__ B, long Bs_z,
    const float* __restrict__ bias0, const float* __restrict__ bias1,
    bf16* __restrict__ Cv, long Cs_z,
    int K, int lda, int ldb, int ldc) {
  __shared__ __align__(16) bf16 As[TM * BK];  // 8 KB
  __shared__ __align__(16) bf16 Bs[TN * BK];  // 8 KB
  const int tid  = threadIdx.x;
  const int wave = tid >> 6;
  const int lane = tid & 63;
  const int zb   = blockIdx.z;
  const float* Af = zb ? A1f : A0f;
  B = B + (size_t)zb * Bs_z;
  const float* bias = zb ? bias1 : bias0;

  const int row0 = blockIdx.x * TM;
  const int col0 = blockIdx.y * TN;
  const int wm = (wave & 1) * 64;
  const int wn = (wave >> 1) * 64;
  const int l31  = lane & 31;
  const int half = lane >> 5;

  v16f acc[2][2] = {};

  const size_t sB = (size_t)ldb * 2;

  // XOR-swizzled staging: LDS granule (row*4 + qs) holds global 16B-chunk
  // (row, q = qs ^ ((row>>1)&3)).  A path writes the same slot via ds_write.
  const int row_s = tid >> 2;                        // 0..63
  const int qg    = (tid & 3) ^ ((row_s >> 1) & 3);

  const float* fa0 = Af + (size_t)(row0 + row_s) * lda + qg * 8;
  const float* fa1 = fa0 + (size_t)64 * lda;
  const char*  pb0 = (const char*)B + (size_t)(col0 + row_s) * sB + qg * 16;
  const char*  pb1 = pb0 + 64 * sB;
  char* ldsB = (char*)Bs + wave * 1024;  // wave-uniform base; HW adds lane*16
  char* wA0  = (char*)As + tid * 16;     // linear slot (row_s, tid&3)
  char* wA1  = wA0 + 4096;

  const int swz  = (lane >> 1) & 3;
  const int off0 = (half ^ swz) * 8;
  const int off1 = off0 ^ 16;
  const int raA0 = (wm + l31) * BK,      raA1 = (wm + 32 + l31) * BK;
  const int raB0 = (wn + l31) * BK,      raB1 = (wn + 32 + l31) * BK;

  const int kIters = K / BK;
  for (int kt = 0; kt < kIters; ++kt) {
    const float4 x00 = *(const float4*)(fa0);
    const float4 x01 = *(const float4*)(fa0 + 4);
    const float4 x10 = *(const float4*)(fa1);
    const float4 x11 = *(const float4*)(fa1 + 4);
    gload_lds16(pb0, ldsB);
    gload_lds16(pb1, ldsB + 4096);
    fa0 += BK; fa1 += BK; pb0 += BK * 2; pb1 += BK * 2;
    v8bf w0, w1;
    w0[0]=(bf16)x00.x; w0[1]=(bf16)x00.y; w0[2]=(bf16)x00.z; w0[3]=(bf16)x00.w;
    w0[4]=(bf16)x01.x; w0[5]=(bf16)x01.y; w0[6]=(bf16)x01.z; w0[7]=(bf16)x01.w;
    w1[0]=(bf16)x10.x; w1[1]=(bf16)x10.y; w1[2]=(bf16)x10.z; w1[3]=(bf16)x10.w;
    w1[4]=(bf16)x11.x; w1[5]=(bf16)x11.y; w1[6]=(bf16)x11.z; w1[7]=(bf16)x11.w;
    *(v8bf*)wA0 = w0;
    *(v8bf*)wA1 = w1;
    __syncthreads();  // drains lgkm (ds_write) + vmcnt (gload_lds) + barrier

    v8bf a[2][2], b[2][2];
    a[0][0] = *(const v8bf*)&As[raA0 + off0];
    a[0][1] = *(const v8bf*)&As[raA0 + off1];
    a[1][0] = *(const v8bf*)&As[raA1 + off0];
    a[1][1] = *(const v8bf*)&As[raA1 + off1];
    b[0][0] = *(const v8bf*)&Bs[raB0 + off0];
    b[0][1] = *(const v8bf*)&Bs[raB0 + off1];
    b[1][0] = *(const v8bf*)&Bs[raB1 + off0];
    b[1][1] = *(const v8bf*)&Bs[raB1 + off1];
#pragma unroll
    for (int kk = 0; kk < 2; ++kk)
#pragma unroll
      for (int i = 0; i < 2; ++i)
#pragma unroll
        for (int j = 0; j < 2; ++j)
          acc[i][j] = __builtin_amdgcn_mfma_f32_32x32x16_bf16(a[i][kk], b[j][kk], acc[i][j], 0, 0, 0);
    __syncthreads();
  }

  // epilogue: 32x32 C/D layout col=lane&31, row=(reg&3)+8*(reg>>2)+4*(lane>>5)
#pragma unroll
  for (int i = 0; i < 2; ++i) {
    const int rb = row0 + wm + i * 32 + 4 * half;
#pragma unroll
    for (int j = 0; j < 2; ++j) {
      const int gcol = col0 + wn + j * 32 + l31;
      const float badd = bias[gcol];
#pragma unroll
      for (int blk = 0; blk < 4; ++blk)
#pragma unroll
        for (int rr = 0; rr < 4; ++rr) {
          const int grow = rb + 8 * blk + rr;
          Cv[(size_t)zb * Cs_z + (size_t)grow * ldc + gcol] =
              (bf16)(acc[i][j][4 * blk + rr] + badd);
        }
    }
  }
}

// ---------------- 256x256 8-phase kernel (MODE 1/2/3) ---------------------
#define FENCE() asm volatile("" ::: "memory")
#define BAR8()  do { FENCE(); __builtin_amdgcn_s_barrier(); FENCE(); } while (0)
#define WAIT_LGKM0() asm volatile("s_waitcnt lgkmcnt(0)" ::: "memory")
#define WAIT_VM6()   asm volatile("s_waitcnt vmcnt(6)" ::: "memory")
#define WAIT_VM0()   asm volatile("s_waitcnt vmcnt(0)" ::: "memory")

// LDS sections (16 KiB each, per dbuf): 0=A rows0-127, 1=A rows128-255,
// 2=B rows0-127, 3=B rows128-255.  Stage issue points per tile t:
//   ph0: (t+1).A1 -> dn   (section1 of dn last read in t-1 ph2, drained)
//   ph1: (t+2).B0,B1 -> d (all B reads of tile t drained end-ph0)
//   ph3: (t+2).A0 -> d    (A0 last read in ph2, drained)
// Boundary: vmcnt(6) keeps the 6 (t+2) loads in flight, retires (t+1).A1.
template <int MODE>
__global__ __launch_bounds__(512, 2) void gemm_nt8(
    const bf16* __restrict__ A, long As_z,
    const bf16* __restrict__ B, long Bs_z,
    const float* __restrict__ bias0,
    void* __restrict__ Cv, long Cs_z,
    int K, int lda, int ldb, int ldc) {
  __shared__ __align__(16) bf16 lds[2][4][8192];  // 128 KiB
  char* ldsBase = (char*)&lds[0][0][0];
  const int tid = threadIdx.x;
  const int w   = tid >> 6;   // 0..7
  const int l   = tid & 63;
  const int zb  = blockIdx.z;
  A += (size_t)zb * As_z;
  B += (size_t)zb * Bs_z;

  // XCD-chunked bijective remap (m204) with y-fastest logical order:
  // dispatch id d -> XCD d%8; logical L = (d%8)*(nwg/8)+d/8 (nwg%8==0);
  // lx = L/NY, ly = L%NY so same-lx (A-panel sharers) land on one XCD.
  const int NX = gridDim.x, NY = gridDim.y;
  const int nwg = NX * NY;
  const int d_id = blockIdx.x + NX * blockIdx.y;
  const int L = (d_id & 7) * (nwg >> 3) + (d_id >> 3);
  const int lx = L / NY, ly = L % NY;

  const int row0 = lx * 256;
  const int col0 = ly * 256;
  const int wmi  = w >> 2;    // M half (0..1): wave owns 128 rows
  const int wni  = w & 3;     // N quarter (0..3): wave owns 64 cols
  const int l4 = l & 15, lh = l >> 4;

  // staging: per half-tile (128 rows x 64 cols), wave-issue wi=i*8+w covers
  // rows wi*8+(l>>3); global 16B chunk pre-swizzled cg=(l&7)^(l>>3) so the
  // linear global_load_lds dest realizes LDS slot(r,c) = chunk c^(r&7).
  const int rsub = l >> 3;
  const int cg   = (l & 7) ^ rsub;
  const size_t sA = (size_t)lda * 2, sB = (size_t)ldb * 2;
  const size_t sA64 = sA * 64, sB64 = sB * 64;
  const char* pA0 = (const char*)A + (size_t)(row0 +       w * 8 + rsub) * sA + cg * 16;
  const char* pA1 = (const char*)A + (size_t)(row0 + 128 + w * 8 + rsub) * sA + cg * 16;
  const char* pB0 = (const char*)B + (size_t)(col0 +       w * 8 + rsub) * sB + cg * 16;
  const char* pB1 = (const char*)B + (size_t)(col0 + 128 + w * 8 + rsub) * sB + cg * 16;
  const int wq = w * 1024;

  // ds_read offsets: logical (r = frag*16 + l4, chunk = kk*4 + lh) at slot
  // (chunk ^ (r&7)); r&7 == l&7.  off1 = off0 ^ 64.
  const int off0 = l4 * 128 + ((lh ^ (l & 7)) << 4);
  const int off1 = off0 ^ 64;

  v4f acc[8][4] = {};  // 8 M-frags x 4 N-frags x f32x4

#define STAGE_K(ptr, sec, d, s64)                                   \
  do {                                                              \
    char* _lb = ldsBase + (d) * 65536 + (sec) * 16384 + wq;         \
    gload_lds16(ptr, _lb);                                          \
    gload_lds16((ptr) + (s64), _lb + 8192);                         \
    (ptr) += 128;                                                   \
  } while (0)

#define READ_A(MOFF)                                                         \
  _Pragma("unroll") for (int mm = 0; mm < 4; ++mm) {                         \
    a_[mm][0] = *(const v8bf*)(aB + ((MOFF) + mm) * 2048 + off0);            \
    a_[mm][1] = *(const v8bf*)(aB + ((MOFF) + mm) * 2048 + off1);            \
  }
#define READ_B()                                                             \
  _Pragma("unroll") for (int nn = 0; nn < 4; ++nn) {                         \
    b_[nn][0] = *(const v8bf*)(bB + nn * 2048 + off0);                       \
    b_[nn][1] = *(const v8bf*)(bB + nn * 2048 + off1);                       \
  }
#define MFMA_Q(M0, N0)                                                       \
  _Pragma("unroll") for (int mm = 0; mm < 4; ++mm)                           \
  _Pragma("unroll") for (int nn = 0; nn < 2; ++nn)                           \
  _Pragma("unroll") for (int kk = 0; kk < 2; ++kk)                           \
    acc[(M0) + mm][(N0) + nn] = __builtin_amdgcn_mfma_f32_16x16x32_bf16(     \
        a_[mm][kk], b_[(N0) + nn][kk], acc[(M0) + mm][(N0) + nn], 0, 0, 0);

  const int nt = K >> 6;  // K-tiles of 64 (callers guarantee nt >= 2)

  // prologue: tile0 fully + tile1 {B0,B1,A0} = 7 half-tiles (14 loads);
  // vmcnt(6) -> tile0's 8 loads retired.
  STAGE_K(pB0, 2, 0, sB64);
  STAGE_K(pB1, 3, 0, sB64);
  STAGE_K(pA0, 0, 0, sA64);
  STAGE_K(pA1, 1, 0, sA64);
  STAGE_K(pB0, 2, 1, sB64);
  STAGE_K(pB1, 3, 1, sB64);
  STAGE_K(pA0, 0, 1, sA64);
  WAIT_VM6();
  BAR8();

  v8bf a_[4][2], b_[4][2];

  for (int t = 0; t < nt - 1; ++t) {
    const int d  = t & 1;
    const int dn = d ^ 1;
    const char* aB = ldsBase + d * 65536 + wmi * 16384;
    const char* bB = ldsBase + d * 65536 + 32768 + (wni >> 1) * 16384 + (wni & 1) * 8192;
    const bool pf = (t < nt - 2);
    // -- phase 0: read all B + A(m0-3); stage (t+1).A1 -> buf dn
    READ_A(0);
    READ_B();
    STAGE_K(pA1, 1, dn, sA64);
    BAR8();
    WAIT_LGKM0();
    __builtin_amdgcn_s_setprio(1);
    MFMA_Q(0, 0);
    __builtin_amdgcn_s_setprio(0);
    BAR8();
    // -- phase 1: stage (t+2).B0 + B1 -> buf d (B reads drained end-ph0)
    if (pf) { STAGE_K(pB0, 2, d, sB64); STAGE_K(pB1, 3, d, sB64); }
    BAR8();
    WAIT_LGKM0();
    __builtin_amdgcn_s_setprio(1);
    MFMA_Q(0, 2);
    __builtin_amdgcn_s_setprio(0);
    BAR8();
    // -- phase 2: read A(m4-7)
    READ_A(4);
    BAR8();
    WAIT_LGKM0();
    __builtin_amdgcn_s_setprio(1);
    MFMA_Q(4, 0);
    __builtin_amdgcn_s_setprio(0);
    BAR8();
    // -- phase 3: stage (t+2).A0 -> buf d; tile-boundary counted wait
    if (pf) STAGE_K(pA0, 0, d, sA64);
    BAR8();
    WAIT_LGKM0();
    __builtin_amdgcn_s_setprio(1);
    MFMA_Q(4, 2);
    __builtin_amdgcn_s_setprio(0);
    if (pf) WAIT_VM6(); else WAIT_VM0();
    BAR8();
  }
  // tail tile (no prefetch, no barriers needed)
  {
    const int d = (nt - 1) & 1;
    const char* aB = ldsBase + d * 65536 + wmi * 16384;
    const char* bB = ldsBase + d * 65536 + 32768 + (wni >> 1) * 16384 + (wni & 1) * 8192;
    READ_A(0);
    READ_B();
    MFMA_Q(0, 0);
    MFMA_Q(0, 2);
    READ_A(4);
    MFMA_Q(4, 0);
    MFMA_Q(4, 2);
  }

  // epilogue: 16x16 C/D layout col=lane&15, row=(lane>>4)*4+reg [m89/m91]
  const int rbase = row0 + wmi * 128 + 4 * lh;
#pragma unroll
  for (int mm = 0; mm < 8; ++mm) {
    const int rb = rbase + mm * 16;
#pragma unroll
    for (int nn = 0; nn < 4; ++nn) {
      const int gcol = col0 + wni * 64 + nn * 16 + l4;
      if (MODE == 1) {
        // batch-transposed vpT store; 4 consecutive s -> one 8B store
        const int b = rb >> 12;
        bf16* cb = &((bf16*)Cv)[((size_t)(b * DIMV + gcol)) * SEQ];
        const int s0 = rb & 4095;
        const float badd = bias0[gcol];
        v4bf o;
#pragma unroll
        for (int rr = 0; rr < 4; ++rr) o[rr] = (bf16)(acc[mm][nn][rr] + badd);
        *(v4bf*)&cb[s0] = o;
      } else if (MODE == 2) {
#pragma unroll
        for (int rr = 0; rr < 4; ++rr) {
          float v = acc[mm][nn][rr];
          v = 1.f / (1.f + __expf(v * -0.0625f));  // sigmoid(v/16)
          ((bf16*)Cv)[(size_t)zb * Cs_z + (size_t)(rb + rr) * ldc + gcol] = (bf16)v;
        }
      } else {  // MODE 3: f32 out
#pragma unroll
        for (int rr = 0; rr < 4; ++rr)
          ((float*)Cv)[(size_t)zb * Cs_z + (size_t)(rb + rr) * ldc + gcol] = acc[mm][nn][rr];
      }
    }
  }
#undef STAGE_K
#undef READ_A
#undef READ_B
#undef MFMA_Q
}

extern "C" void kernel_launch(void* const* d_in, const int* in_sizes, int n_in,
                              void* d_out, int out_size, void* d_ws, size_t ws_size,
                              hipStream_t stream) {
  const float* q  = (const float*)d_in[0];
  const float* k  = (const float*)d_in[1];
  const float* v  = (const float*)d_in[2];
  const float* Wq = (const float*)d_in[3];
  const float* bq = (const float*)d_in[4];
  const float* Wk = (const float*)d_in[5];
  const float* bk = (const float*)d_in[6];
  const float* Wv = (const float*)d_in[7];
  const float* bv = (const float*)d_in[8];
  float* out = (float*)d_out;

  const size_t MB = 1024 * 1024;
  char* ws = (char*)d_ws;

  int g;
  size_t zcap;
  if (ws_size >= 188 * MB)      { g = 4; zcap = 128 * MB; }
  else if (ws_size >= 121 * MB) { g = 2; zcap = 64 * MB; }
  else                          { g = 1; zcap = 64 * MB; }

  bf16 *castA, *zbuf, *Wq16, *Wk16, *Wv16, *qp16, *kp16, *vpT;
  if (g >= 2) {
    castA = (bf16*)ws;               // 32 MB (v16 only now; q/k fused)
    zbuf  = (bf16*)ws;               // g*32 MB (cast dead by then)
    char* p = ws + zcap;
    Wq16 = (bf16*)p;             p += 524288;
    Wk16 = (bf16*)p;             p += 524288;
    Wv16 = (bf16*)p;             p += 2097152;
    qp16 = (bf16*)p;             p += 8388608;
    kp16 = (bf16*)p;             p += 8388608;
    vpT  = (bf16*)p;
  } else {
    castA = (bf16*)ws;
    zbuf  = castA;
    char* p = ws + 32 * MB;
    Wq16 = (bf16*)p;             p += 524288;
    Wk16 = (bf16*)p;             p += 524288;
    Wv16 = (bf16*)p;             p += 2097152;
    qp16 = (bf16*)p;             p += 8388608;
    kp16 = (bf16*)p;             p += 8388608;
    vpT  = (bf16*)p;
  }

  const int NQKV = BATCH * SEQ * DIMV;  // 16777216

  auto cast = [&](const float* src, bf16* dst, int n) {
    int n4 = n / 4;
    cast_f32_bf16<<<dim3((n4 + 255) / 256), dim3(256), 0, stream>>>(src, dst, n4);
  };

  cast(Wq, Wq16, QKD * DIMV);
  cast(Wk, Wk16, QKD * DIMV);
  cast(Wv, Wv16, DIMV * DIMV);

  // qp/kp dual launch with fused fp32->bf16 A-cast:
  // zb=0 -> qp = q@Wq16^T+bq; zb=1 -> kp = k@Wk16^T+bk
  gemm_proj<<<dim3(BATCH * SEQ / TM, QKD / TN, 2), dim3(256), 0, stream>>>(
      q, k, Wq16, (long)(QKD * DIMV), bq, bk,
      qp16, (long)(kp16 - qp16), DIMV, DIMV, DIMV, QKD);

  // vpT: 8-phase 256^2, flat M=16384, batch-decomposed transposed store
  cast(v, castA, NQKV);  // v16
  gemm_nt8<1><<<dim3(BATCH * SEQ / 256, DIMV / 256, 1), dim3(512), 0, stream>>>(
      castA, 0L, Wv16, 0L, bv,
      vpT, 0L, DIMV, DIMV, DIMV, 0);

  // per group: z = sigmoid(qp@kp^T/16); out = z @ vp  (both 8-phase 256^2)
  const long zstride = (long)SEQ * SEQ;
  for (int ig = 0; ig < BATCH / g; ++ig) {
    const size_t b0 = (size_t)ig * g;
    gemm_nt8<2><<<dim3(SEQ / 256, SEQ / 256, g), dim3(512), 0, stream>>>(
        qp16 + b0 * SEQ * QKD, (long)(SEQ * QKD),
        kp16 + b0 * SEQ * QKD, (long)(SEQ * QKD),
        nullptr, zbuf, zstride, QKD, QKD, QKD, SEQ);
    gemm_nt8<3><<<dim3(SEQ / 256, DIMV / 256, g), dim3(512), 0, stream>>>(
        zbuf, zstride, vpT + b0 * DIMV * SEQ, (long)(DIMV * SEQ),
        nullptr, out + b0 * SEQ * DIMV, (long)(SEQ * DIMV),
        SEQ, SEQ, SEQ, DIMV);
  }
}